// Round 16
// baseline (81.646 us; speedup 1.0000x reference)
//
#include <hip/hip_runtime.h>
#include <hip/hip_bf16.h>
#include <math.h>

#define DEV static __device__ __forceinline__

typedef unsigned short u16;
typedef unsigned int u32;
typedef __attribute__((ext_vector_type(4))) float f32x4;
typedef __attribute__((ext_vector_type(16))) float f32x16;
typedef __attribute__((ext_vector_type(8))) __bf16 bf16x8;
typedef __attribute__((ext_vector_type(4))) u16 u16x4;
typedef __attribute__((ext_vector_type(4))) u32 u32x4;

// float -> bf16 bits, round-to-nearest-even
DEV u16 f2bf(float f) {
  unsigned u = __float_as_uint(f);
  u += 0x7fffu + ((u >> 16) & 1u);
  return (u16)(u >> 16);
}
DEV float bf2f(u16 x) { return __uint_as_float((u32)x << 16); }

// single-instruction transcendentals
DEV float fexp2(float x) { return __builtin_amdgcn_exp2f(x); }
DEV float fsin_rev(float rev) { return __builtin_amdgcn_sinf(rev); }  // revolutions
DEV float fcos_rev(float rev) { return __builtin_amdgcn_cosf(rev); }

DEV u32 cvt_pk_bf16(float lo, float hi) {
  u32 r;
  asm("v_cvt_pk_bf16_f32 %0, %1, %2" : "=v"(r) : "v"(lo), "v"(hi));
  return r;
}

// v_permlane32_swap_b32: a' = {a.lo, b.lo}, b' = {a.hi, b.hi}
DEV void perm32swap(u32& a, u32& b) {
  asm("v_permlane32_swap_b32 %0, %1" : "+v"(a), "+v"(b));
}

DEV void gl2lds16(const void* g, void* l) {
  __builtin_amdgcn_global_load_lds(
      (const __attribute__((address_space(1))) void*)g,
      (__attribute__((address_space(3))) void*)l, 16, 0, 0);
}

// Stage RPW rows (per wave) x 64 bf16 cols from global into linear LDS [rows][64]
// with XOR bank-swizzle applied on the GLOBAL source slot (both-sides-or-neither).
template<int RPW>
DEV void stage_rows(const u16* __restrict__ g, int gstride, u16* lds, int wave, int lane) {
  const int r_in = lane >> 3, slot = lane & 7;
  const int base_row = wave * RPW;
#pragma unroll
  for (int i = 0; i < RPW / 8; ++i) {
    const int row = base_row + i * 8 + r_in;
    const int sslot = slot ^ (row & 7);
    gl2lds16(g + (size_t)row * gstride + sslot * 8,
             lds + (size_t)(base_row + i * 8) * 64);
  }
}

// Read an 8-bf16 slot (16B) from the swizzled [rows][64] tile.
DEV bf16x8 frag_read(const u16* lds, int row, int kslot) {
  const int slot = kslot ^ (row & 7);
  return *(const bf16x8*)(lds + row * 64 + slot * 8);
}

DEV f32x4 mfma16(bf16x8 a, bf16x8 b, f32x4 c) {
  return __builtin_amdgcn_mfma_f32_16x16x32_bf16(a, b, c, 0, 0, 0);
}
DEV f32x16 mfma32(bf16x8 a, bf16x8 b, f32x16 c) {
  return __builtin_amdgcn_mfma_f32_32x32x16_bf16(a, b, c, 0, 0, 0);
}

// ---------------------------------------------------------------------------
// MERGED prep kernel (r13, unchanged). grid (32, 16, 9), block 256.
//  z < 8 : x (B,C,H,W) -> Xp bf16 (B*S, D) row-major, + 2D positional encoding
//          (HW transcendentals only). Xp doubles as the residual.
//  z == 8: pack weights fp32 -> bf16 MFMA B-fragment layout.
__global__ __launch_bounds__(256) void prep_x(
    const float* __restrict__ x, u16* __restrict__ Xp,
    const float* __restrict__ w0, const float* __restrict__ w1,
    const float* __restrict__ w2, const float* __restrict__ w3,
    u16* __restrict__ Wpk) {
  const int t = threadIdx.x;
  if (blockIdx.z == 8) {
    const int flat = blockIdx.x + 32 * blockIdx.y;      // 0..511
    const int wsel = flat >> 7, bx = flat & 127;
    const float* src = (wsel == 0) ? w0 : (wsel == 1) ? w1 : (wsel == 2) ? w2 : w3;
    const int lane = t & 63, wave = t >> 6;
    const int c16 = bx >> 2;
    const int kchunk = (bx & 3) * 4 + wave;
    const int cl = lane & 15, ko = lane >> 4;
    const float* s = src + (size_t)(c16 * 16 + cl) * 512 + kchunk * 32 + ko * 8;
    const f32x4 a = *(const f32x4*)(s);
    const f32x4 b = *(const f32x4*)(s + 4);
    u16x4 lo, hi;
#pragma unroll
    for (int j = 0; j < 4; ++j) { lo[j] = f2bf(a[j]); hi[j] = f2bf(b[j]); }
    u16* d = Wpk + (size_t)wsel * 262144
                 + (size_t)(c16 * 16 + kchunk) * 512 + lane * 8;
    *(u16x4*)(d) = lo;
    *(u16x4*)(d + 4) = hi;
    return;
  }
  __shared__ float tile[32][33];
  const int b = blockIdx.z, c0 = blockIdx.y * 32, s0 = blockIdx.x * 32;
  const int cf = t >> 5, sf = t & 31;
#pragma unroll
  for (int i = 0; i < 4; ++i) {
    const int c = c0 + cf + i * 8;
    tile[cf + i * 8][sf] = x[((size_t)b * 512 + c) * 1024 + s0 + sf];
  }
  __syncthreads();
  const int cl = t & 31, sl = t >> 5;
  const int cg = c0 + cl;
  const int j = cg >> 2;
  const float dv = fexp2((float)j * -0.051905126482615f);   // 10000^(-j/256)
  const float dv_rev = dv * 0.15915494309189535f;           // /(2*pi)
#pragma unroll
  for (int i = 0; i < 4; ++i) {
    const int s = s0 + sl + i * 8;
    const float pos = (cg & 2) ? (float)(s & 31) : (float)(s >> 5);
    float rev = pos * dv_rev;
    rev = rev - floorf(rev);                            // reduce to [0,1)
    const float pe = (cg & 1) ? fcos_rev(rev) : fsin_rev(rev);
    const float v = tile[cl][sl + i * 8] + pe;
    Xp[((size_t)b * 1024 + s) * 512 + cg] = f2bf(v);
  }
}

// ---------------------------------------------------------------------------
// Fused QKV GEMM with DOUBLE-BUFFERED A staging (r15, unchanged).
__global__ __launch_bounds__(256) void gemm_qkv(
    const u16* __restrict__ Xp, const u16* __restrict__ Wpk,
    u16* __restrict__ Qb, u16* __restrict__ Kb, u16* __restrict__ Vtb,
    float qscale) {
  __shared__ __align__(16) u16 smem[16896];       // A dbuf 2x8K | V-transpose reuse
  const int t = threadIdx.x, lane = t & 63, wave = t >> 6;
  const int bn0 = blockIdx.x * 128, bm0 = blockIdx.y * 128;
  const int wr = wave >> 1, wc = wave & 1;
  const int colbase = bn0 + wc * 64;
  const int w = colbase >> 9;                     // 0=Wq 1=Wk 2=Wv
  const int cb16 = (colbase & 511) >> 4;          // base c16 within weight
  const u16* Bf = Wpk + (size_t)w * 262144;
  const u16* Ag = Xp + (size_t)bm0 * 512;
  f32x4 acc[4][4] = {};
  stage_rows<32>(Ag, 512, smem, wave, lane);
  __syncthreads();
  int cur = 0;
  for (int kt = 0; kt < 512; kt += 64) {
    if (kt < 448)
      stage_rows<32>(Ag + kt + 64, 512, smem + (cur ^ 1) * 8192, wave, lane);
    u16* Asc = smem + cur * 8192;
#pragma unroll
    for (int ks = 0; ks < 2; ++ks) {
      const int kc = (kt >> 5) + ks;
      bf16x8 af[4], bfr[4];
#pragma unroll
      for (int n = 0; n < 4; ++n)
        bfr[n] = *(const bf16x8*)(Bf + (size_t)((cb16 + n) * 16 + kc) * 512 + lane * 8);
#pragma unroll
      for (int m = 0; m < 4; ++m)
        af[m] = frag_read(Asc, wr * 64 + m * 16 + (lane & 15), ks * 4 + (lane >> 4));
#pragma unroll
      for (int m = 0; m < 4; ++m)
#pragma unroll
        for (int n = 0; n < 4; ++n)
          acc[m][n] = mfma16(af[m], bfr[n], acc[m][n]);
    }
    __syncthreads();   // drains next-tile loads (landed under compute) + read fence
    cur ^= 1;
  }
  const int cl = lane & 15, rg = (lane >> 4) * 4;
  if (bn0 >= 1024) {
    // ---- V region: transpose through LDS, then coalesced stores
#pragma unroll
    for (int m = 0; m < 4; ++m)
#pragma unroll
      for (int n = 0; n < 4; ++n) {
        const int dvL = wc * 64 + n * 16 + cl;
        const int rowL0 = wr * 64 + m * 16 + rg;
        u16x4 pk;
#pragma unroll
        for (int r = 0; r < 4; ++r) pk[r] = f2bf(acc[m][n][r]);
        *(u16x4*)(smem + dvL * 132 + rowL0) = pk;
      }
    __syncthreads();
    const int dvg0 = bn0 - 1024;
#pragma unroll
    for (int i = 0; i < 16; ++i) {
      const int idx = i * 256 + t;          // 4096 u16x4 total
      const int dv = idx >> 5, ch = (idx & 31) * 4;
      const u16x4 v = *(const u16x4*)(smem + dv * 132 + ch);
      *(u16x4*)(Vtb + (size_t)(dvg0 + dv) * 8192 + bm0 + ch) = v;
    }
  } else {
    u16* dst = (bn0 >= 512) ? Kb : Qb;
    const float al = (bn0 >= 512) ? 1.0f : qscale;
    const int cb = (bn0 & 511) + wc * 64;
#pragma unroll
    for (int m = 0; m < 4; ++m)
#pragma unroll
      for (int n = 0; n < 4; ++n) {
        const int col = cb + n * 16 + cl;
#pragma unroll
        for (int r = 0; r < 4; ++r) {
          const int row = bm0 + wr * 64 + m * 16 + rg + r;
          dst[(size_t)row * 512 + col] = f2bf(acc[m][n][r] * al);
        }
      }
  }
}

// ---------------------------------------------------------------------------
// FUSED out-proj + bias + residual + LayerNorm + NCHW transpose (r15, unchanged).
__global__ __launch_bounds__(512) void gemm_ln(
    const u16* __restrict__ A, const u16* __restrict__ Wpk,
    const u16* __restrict__ residb, const float* __restrict__ bias,
    const float* __restrict__ gamma, const float* __restrict__ beta,
    float* __restrict__ out) {
  __shared__ __align__(16) u16 smem[35200];          // As 32x64 | fsm reuse (70.4KB)
  __shared__ float redsum[8][32], redsq[8][32], srow[32][2];
  const int t = threadIdx.x, lane = t & 63, wave = t >> 6;
  const int m0 = blockIdx.x * 32;
  const int b = m0 >> 10, s0 = m0 & 1023;
  u16* As = smem;
  const u16* Bf = Wpk + (size_t)3 * 262144;        // Wo
  const u16* Ag = A + (size_t)m0 * 512;
  f32x4 acc[2][4] = {};
  for (int kt = 0; kt < 512; kt += 64) {
    __syncthreads();
    if (wave < 4) stage_rows<8>(Ag + kt, 512, As, wave, lane);  // 32 rows of A
    __syncthreads();
#pragma unroll
    for (int ks = 0; ks < 2; ++ks) {
      const int kc = (kt >> 5) + ks;
      bf16x8 af[2], bfr[4];
#pragma unroll
      for (int n = 0; n < 4; ++n)
        bfr[n] = *(const bf16x8*)(Bf + (size_t)((wave * 4 + n) * 16 + kc) * 512 + lane * 8);
#pragma unroll
      for (int m = 0; m < 2; ++m)
        af[m] = frag_read(As, m * 16 + (lane & 15), ks * 4 + (lane >> 4));
#pragma unroll
      for (int m = 0; m < 2; ++m)
#pragma unroll
        for (int n = 0; n < 4; ++n)
          acc[m][n] = mfma16(af[m], bfr[n], acc[m][n]);
    }
  }
  // ---- epilogue: bias + resid, partial LN stats, stage to LDS (transposed)
  __syncthreads();                 // done reading staging LDS; reuse as float
  float* fsm = (float*)smem;       // per wave: [64 cols][33 rows]
  float* fw = fsm + wave * (64 * 33);
  const int cl = lane & 15, rg = (lane >> 4) * 4;
  float psum[8], psq[8];
#pragma unroll
  for (int i = 0; i < 8; ++i) { psum[i] = 0.f; psq[i] = 0.f; }
#pragma unroll
  for (int m = 0; m < 2; ++m)
#pragma unroll
    for (int n = 0; n < 4; ++n) {
      const int col_l = n * 16 + cl;
      const int col = wave * 64 + col_l;
      const float bi = bias[col];
#pragma unroll
      for (int r = 0; r < 4; ++r) {
        const int row_l = m * 16 + rg + r;
        const float v = acc[m][n][r] + bi
                      + bf2f(residb[(size_t)(m0 + row_l) * 512 + col]);
        fw[col_l * 33 + row_l] = v;
        psum[m * 4 + r] += v;
        psq[m * 4 + r] += v * v;
      }
    }
#pragma unroll
  for (int i = 0; i < 8; ++i) {
#pragma unroll
    for (int off = 8; off >= 1; off >>= 1) {
      psum[i] += __shfl_xor(psum[i], off);
      psq[i]  += __shfl_xor(psq[i], off);
    }
  }
  if (cl == 0) {
#pragma unroll
    for (int m = 0; m < 2; ++m)
#pragma unroll
      for (int r = 0; r < 4; ++r) {
        const int row_l = m * 16 + rg + r;
        redsum[wave][row_l] = psum[m * 4 + r];
        redsq[wave][row_l]  = psq[m * 4 + r];
      }
  }
  __syncthreads();
  if (t < 32) {
    float s = 0.f, q = 0.f;
#pragma unroll
    for (int w = 0; w < 8; ++w) { s += redsum[w][t]; q += redsq[w][t]; }
    const float mean = s * (1.f / 512.f);
    const float var = q * (1.f / 512.f) - mean * mean;
    srow[t][0] = mean;
    srow[t][1] = rsqrtf(var + 1e-5f);
  }
  __syncthreads();
  // ---- normalize + transposed write (contiguous 128B per channel)
  const int row = t & 31, cgrp = t >> 5;           // cgrp 0..15
  const float mean = srow[row][0], rstd = srow[row][1];
  float* outb = out + (size_t)b * 512 * 1024 + s0 + row;
#pragma unroll 4
  for (int cc = 0; cc < 32; ++cc) {
    const int col = cc * 16 + cgrp;
    const float v = (fsm[(col >> 6) * (64 * 33) + (col & 63) * 33 + row] - mean) * rstd;
    outb[(size_t)col * 1024] = v * gamma[col] + beta[col];
  }
}

// ---------------------------------------------------------------------------
// Flash attention v9: counted-vmcnt double-buffered pipeline (T3+T4) with
// single-instruction exp2 (the r4 attempt lacked this) + defer-max + setprio.
// Grid 1024 x 128 threads (2 waves x 32 q = 64 q/block; b=wg&7 XCD-resident).
// Wave 0 stages K tiles, wave 1 stages V tiles (8 gl2lds each); next tile's
// loads stay IN FLIGHT across the head barrier via s_waitcnt vmcnt(8) —
// never drained to 0 in the main loop. LDS 32KB dbuf -> 4 blocks/CU.
__global__ __launch_bounds__(128, 2) void attn(
    const u16* __restrict__ Qb, const u16* __restrict__ Kb,
    const u16* __restrict__ Vt, u16* __restrict__ Ob) {
  __shared__ __align__(16) u16 Ks[2][64 * 64];
  __shared__ __align__(16) u16 Vs[2][64 * 64];
  const int t = threadIdx.x, lane = t & 63, wave = t >> 6;   // 2 waves
  const int wg = blockIdx.x;
  const int b = wg & 7, h = (wg >> 3) & 7, qt = wg >> 6;     // qt 0..15
  const int ql = lane & 31, hl = lane >> 5;
  const int q0 = qt * 64 + wave * 32;
  bf16x8 bq[4];
  {
    const u16* qrow = Qb + ((size_t)b * 1024 + q0 + ql) * 512 + h * 64 + hl * 8;
#pragma unroll
    for (int c = 0; c < 4; ++c) bq[c] = *(const bf16x8*)(qrow + c * 16);
  }
  f32x16 ot[2] = {};
  float m_run = -1e30f, l_run = 0.f;
  const u16* Kg = Kb + (size_t)b * 1024 * 512 + h * 64;
  const u16* Vg = Vt + (size_t)(h * 64) * 8192 + (size_t)b * 1024;
  const int r_in = lane >> 3, slot = lane & 7;
  // stage tile kv into buffer buf: wave 0 -> K (row-major), wave 1 -> V^T
#define STAGE_TILE(kv, buf)                                                   \
  do {                                                                        \
    if (wave == 0) {                                                          \
      const u16* src = Kg + (size_t)(kv) * 64 * 512;                          \
      _Pragma("unroll")                                                       \
      for (int j = 0; j < 8; ++j) {                                           \
        const int row = j * 8 + r_in;                                         \
        const int ss = slot ^ (row & 7);                                      \
        gl2lds16(src + (size_t)row * 512 + ss * 8, &Ks[buf][j * 512]);        \
      }                                                                       \
    } else {                                                                  \
      const u16* src = Vg + (kv) * 64;                                        \
      _Pragma("unroll")                                                       \
      for (int j = 0; j < 8; ++j) {                                           \
        const int row = j * 8 + r_in;                                         \
        const int ss = slot ^ (row & 7);                                      \
        gl2lds16(src + (size_t)row * 8192 + ss * 8, &Vs[buf][j * 512]);       \
      }                                                                       \
    }                                                                         \
  } while (0)

  STAGE_TILE(0, 0);
  __builtin_amdgcn_sched_barrier(0);
  asm volatile("s_waitcnt vmcnt(0)" ::: "memory");
  __builtin_amdgcn_s_barrier();
  __builtin_amdgcn_sched_barrier(0);
  int cur = 0;
  for (int kv = 0; kv < 16; ++kv) {
    // issue next tile into the other buffer (read last at kv-1; tail barrier
    // of kv-1 guarantees all waves are done with it)
    if (kv < 15) {
      STAGE_TILE(kv + 1, cur ^ 1);
      __builtin_amdgcn_sched_barrier(0);
      asm volatile("s_waitcnt vmcnt(8)" ::: "memory");  // tile kv landed; kv+1 in flight
    } else {
      asm volatile("s_waitcnt vmcnt(0)" ::: "memory");
    }
    __builtin_amdgcn_s_barrier();          // cross-wave: tile kv visible to all
    __builtin_amdgcn_sched_barrier(0);
    // S^T[k][q] = K[k][:] . Q[q][:]
    f32x16 st[2] = {};
    __builtin_amdgcn_s_setprio(1);
#pragma unroll
    for (int c = 0; c < 4; ++c) {
      bf16x8 a0 = frag_read(Ks[cur], ql, c * 2 + hl);
      bf16x8 a1 = frag_read(Ks[cur], 32 + ql, c * 2 + hl);
      st[0] = mfma32(a0, bq[c], st[0]);
      st[1] = mfma32(a1, bq[c], st[1]);
    }
    __builtin_amdgcn_s_setprio(0);
    // ---- online softmax with defer-max
    float m0[8];
#pragma unroll
    for (int i2 = 0; i2 < 8; ++i2)
      m0[i2] = fmaxf(fmaxf(st[0][i2], st[0][i2 + 8]), fmaxf(st[1][i2], st[1][i2 + 8]));
#pragma unroll
    for (int i2 = 0; i2 < 4; ++i2) m0[i2] = fmaxf(m0[i2], m0[i2 + 4]);
    float mx = fmaxf(fmaxf(m0[0], m0[1]), fmaxf(m0[2], m0[3]));
    mx = fmaxf(mx, __shfl_xor(mx, 32));
    if (!__all(mx <= m_run + 8.f)) {
      const float mn = fmaxf(m_run, mx);
      const float sc = fexp2(m_run - mn);
      m_run = mn;
      l_run *= sc;
      ot[0] *= sc;
      ot[1] *= sc;
    }
#pragma unroll
    for (int i2 = 0; i2 < 16; ++i2) {
      st[0][i2] = fexp2(st[0][i2] - m_run);
      st[1][i2] = fexp2(st[1][i2] - m_run);
    }
    float s0[8];
#pragma unroll
    for (int i2 = 0; i2 < 8; ++i2)
      s0[i2] = (st[0][i2] + st[0][i2 + 8]) + (st[1][i2] + st[1][i2 + 8]);
#pragma unroll
    for (int i2 = 0; i2 < 4; ++i2) s0[i2] = s0[i2] + s0[i2 + 4];
    float rs = (s0[0] + s0[1]) + (s0[2] + s0[3]);
    rs += __shfl_xor(rs, 32);
    l_run += rs;
    // ---- pack P -> bf16, redistribute, accumulate O^T += V^T P^T
    __builtin_amdgcn_s_setprio(1);
#pragma unroll
    for (int c = 0; c < 4; ++c) {
      const int kf = c >> 1, i0 = (c & 1) * 4;
      u32 w0 = cvt_pk_bf16(st[kf][2 * i0 + 0], st[kf][2 * i0 + 1]);
      u32 w1 = cvt_pk_bf16(st[kf][2 * i0 + 2], st[kf][2 * i0 + 3]);
      u32 w2 = cvt_pk_bf16(st[kf][2 * i0 + 4], st[kf][2 * i0 + 5]);
      u32 w3 = cvt_pk_bf16(st[kf][2 * i0 + 6], st[kf][2 * i0 + 7]);
      perm32swap(w0, w2);
      perm32swap(w1, w3);
      u32x4 wv; wv.x = w0; wv.y = w1; wv.z = w2; wv.w = w3;
      bf16x8 bp = *(bf16x8*)&wv;
      bf16x8 v0 = frag_read(Vs[cur], ql, c * 2 + hl);
      bf16x8 v1 = frag_read(Vs[cur], 32 + ql, c * 2 + hl);
      ot[0] = mfma32(v0, bp, ot[0]);
      ot[1] = mfma32(v1, bp, ot[1]);
    }
    __builtin_amdgcn_s_setprio(0);
    __builtin_amdgcn_sched_barrier(0);
    __builtin_amdgcn_s_barrier();          // tail: all reads of buf cur done
    __builtin_amdgcn_sched_barrier(0);
    cur ^= 1;
  }
#undef STAGE_TILE
  // ---- write O (packed u16x4: d = df*32 + rq*8 + 4*hl + j)
  const float inv = 1.f / l_run;
  u16* orow = Ob + ((size_t)b * 1024 + q0 + ql) * 512 + h * 64;
#pragma unroll
  for (int df = 0; df < 2; ++df)
#pragma unroll
    for (int rq = 0; rq < 4; ++rq) {
      u16x4 pk;
#pragma unroll
      for (int j = 0; j < 4; ++j) pk[j] = f2bf(ot[df][rq * 4 + j] * inv);
      *(u16x4*)(orow + df * 32 + rq * 8 + 4 * hl) = pk;
    }
}

// ---------------------------------------------------------------------------
extern "C" void kernel_launch(void* const* d_in, const int* in_sizes, int n_in,
                              void* d_out, int out_size, void* d_ws, size_t ws_size,
                              hipStream_t stream) {
  const float* x     = (const float*)d_in[0];
  const float* Wq    = (const float*)d_in[1];
  const float* Wk    = (const float*)d_in[2];
  const float* Wv    = (const float*)d_in[3];
  const float* Wo    = (const float*)d_in[4];
  const float* bo    = (const float*)d_in[5];
  const float* gamma = (const float*)d_in[6];
  const float* beta  = (const float*)d_in[7];
  char* ws = (char*)d_ws;
  const size_t MB = 1048576;
  u16*   Xp    = (u16*)(ws);             //  8 MB bf16 (8192,512): x + PE (also residual)
  u16*   Wpk   = (u16*)(ws + 8 * MB);    //  2 MB packed weight fragments [q][k][v][o]
  u16*   Qb    = (u16*)(ws + 10 * MB);   //  8 MB (prescaled)
  u16*   Kb    = (u16*)(ws + 18 * MB);   //  8 MB
  u16*   Vtb   = (u16*)(ws + 26 * MB);   //  8 MB bf16 V^T (512, 8192)
  u16*   Ob    = (u16*)(ws + 34 * MB);   //  8 MB attention out

  // merged: x+PE prep (z<8) and weight fragment packing (z==8)
  prep_x<<<dim3(32, 16, 9), 256, 0, stream>>>(x, Xp, Wq, Wk, Wv, Wo, Wpk);
  // fused QKV: Q scaled by (1/sqrt(dk))*log2(e); V written transposed
  gemm_qkv<<<dim3(12, 64), 256, 0, stream>>>(Xp, Wpk, Qb, Kb, Vtb,
                                             0.125f * 1.44269504088896f);
  attn<<<1024, 128, 0, stream>>>(Qb, Kb, Vtb, Ob);
  // fused out-proj + bias + residual + LayerNorm + NCHW transpose
  gemm_ln<<<256, 512, 0, stream>>>(Ob, Wpk, Xp, bo, gamma, beta,
                                   (float*)d_out);
}

// Round 17
// 79.890 us; speedup vs baseline: 1.0220x; 1.0220x over previous
//
#include <hip/hip_runtime.h>
#include <hip/hip_bf16.h>
#include <math.h>

#define DEV static __device__ __forceinline__

typedef unsigned short u16;
typedef unsigned int u32;
typedef __attribute__((ext_vector_type(4))) float f32x4;
typedef __attribute__((ext_vector_type(16))) float f32x16;
typedef __attribute__((ext_vector_type(8))) __bf16 bf16x8;
typedef __attribute__((ext_vector_type(4))) u16 u16x4;
typedef __attribute__((ext_vector_type(4))) u32 u32x4;

// float -> bf16 bits, round-to-nearest-even
DEV u16 f2bf(float f) {
  unsigned u = __float_as_uint(f);
  u += 0x7fffu + ((u >> 16) & 1u);
  return (u16)(u >> 16);
}
DEV float bf2f(u16 x) { return __uint_as_float((u32)x << 16); }

// single-instruction transcendentals
DEV float fexp2(float x) { return __builtin_amdgcn_exp2f(x); }
DEV float fsin_rev(float rev) { return __builtin_amdgcn_sinf(rev); }  // revolutions
DEV float fcos_rev(float rev) { return __builtin_amdgcn_cosf(rev); }

DEV u32 cvt_pk_bf16(float lo, float hi) {
  u32 r;
  asm("v_cvt_pk_bf16_f32 %0, %1, %2" : "=v"(r) : "v"(lo), "v"(hi));
  return r;
}

// v_permlane32_swap_b32: a' = {a.lo, b.lo}, b' = {a.hi, b.hi}
DEV void perm32swap(u32& a, u32& b) {
  asm("v_permlane32_swap_b32 %0, %1" : "+v"(a), "+v"(b));
}

DEV void gl2lds16(const void* g, void* l) {
  __builtin_amdgcn_global_load_lds(
      (const __attribute__((address_space(1))) void*)g,
      (__attribute__((address_space(3))) void*)l, 16, 0, 0);
}

// Stage RPW rows (per wave) x 64 bf16 cols from global into linear LDS [rows][64]
// with XOR bank-swizzle applied on the GLOBAL source slot (both-sides-or-neither).
template<int RPW>
DEV void stage_rows(const u16* __restrict__ g, int gstride, u16* lds, int wave, int lane) {
  const int r_in = lane >> 3, slot = lane & 7;
  const int base_row = wave * RPW;
#pragma unroll
  for (int i = 0; i < RPW / 8; ++i) {
    const int row = base_row + i * 8 + r_in;
    const int sslot = slot ^ (row & 7);
    gl2lds16(g + (size_t)row * gstride + sslot * 8,
             lds + (size_t)(base_row + i * 8) * 64);
  }
}

// Read an 8-bf16 slot (16B) from the swizzled [rows][64] tile.
DEV bf16x8 frag_read(const u16* lds, int row, int kslot) {
  const int slot = kslot ^ (row & 7);
  return *(const bf16x8*)(lds + row * 64 + slot * 8);
}

DEV f32x4 mfma16(bf16x8 a, bf16x8 b, f32x4 c) {
  return __builtin_amdgcn_mfma_f32_16x16x32_bf16(a, b, c, 0, 0, 0);
}
DEV f32x16 mfma32(bf16x8 a, bf16x8 b, f32x16 c) {
  return __builtin_amdgcn_mfma_f32_32x32x16_bf16(a, b, c, 0, 0, 0);
}

// ---------------------------------------------------------------------------
// MERGED prep kernel. grid (32, 16, 9), block 256.
//  z < 8 : x (B,C,H,W) -> Xp bf16 (B*S, D) row-major, + 2D positional encoding
//          (HW transcendentals only). Xp doubles as the residual.
//  z == 8: pack weights fp32 -> bf16 MFMA B-fragment layout.
__global__ __launch_bounds__(256) void prep_x(
    const float* __restrict__ x, u16* __restrict__ Xp,
    const float* __restrict__ w0, const float* __restrict__ w1,
    const float* __restrict__ w2, const float* __restrict__ w3,
    u16* __restrict__ Wpk) {
  const int t = threadIdx.x;
  if (blockIdx.z == 8) {
    const int flat = blockIdx.x + 32 * blockIdx.y;      // 0..511
    const int wsel = flat >> 7, bx = flat & 127;
    const float* src = (wsel == 0) ? w0 : (wsel == 1) ? w1 : (wsel == 2) ? w2 : w3;
    const int lane = t & 63, wave = t >> 6;
    const int c16 = bx >> 2;
    const int kchunk = (bx & 3) * 4 + wave;
    const int cl = lane & 15, ko = lane >> 4;
    const float* s = src + (size_t)(c16 * 16 + cl) * 512 + kchunk * 32 + ko * 8;
    const f32x4 a = *(const f32x4*)(s);
    const f32x4 b = *(const f32x4*)(s + 4);
    u16x4 lo, hi;
#pragma unroll
    for (int j = 0; j < 4; ++j) { lo[j] = f2bf(a[j]); hi[j] = f2bf(b[j]); }
    u16* d = Wpk + (size_t)wsel * 262144
                 + (size_t)(c16 * 16 + kchunk) * 512 + lane * 8;
    *(u16x4*)(d) = lo;
    *(u16x4*)(d + 4) = hi;
    return;
  }
  __shared__ float tile[32][33];
  const int b = blockIdx.z, c0 = blockIdx.y * 32, s0 = blockIdx.x * 32;
  const int cf = t >> 5, sf = t & 31;
#pragma unroll
  for (int i = 0; i < 4; ++i) {
    const int c = c0 + cf + i * 8;
    tile[cf + i * 8][sf] = x[((size_t)b * 512 + c) * 1024 + s0 + sf];
  }
  __syncthreads();
  const int cl = t & 31, sl = t >> 5;
  const int cg = c0 + cl;
  const int j = cg >> 2;
  const float dv = fexp2((float)j * -0.051905126482615f);   // 10000^(-j/256)
  const float dv_rev = dv * 0.15915494309189535f;           // /(2*pi)
#pragma unroll
  for (int i = 0; i < 4; ++i) {
    const int s = s0 + sl + i * 8;
    const float pos = (cg & 2) ? (float)(s & 31) : (float)(s >> 5);
    float rev = pos * dv_rev;
    rev = rev - floorf(rev);                            // reduce to [0,1)
    const float pe = (cg & 1) ? fcos_rev(rev) : fsin_rev(rev);
    const float v = tile[cl][sl + i * 8] + pe;
    Xp[((size_t)b * 1024 + s) * 512 + cg] = f2bf(v);
  }
}

// ---------------------------------------------------------------------------
// Fused QKV GEMM with DOUBLE-BUFFERED A staging (T3-minimum 2-phase): next
// K-step's stage issued BEFORE this step's compute; ONE barrier per step.
// B operand direct from packed fragments. grid (12, 64). Epilogue: Q scaled
// row-major, K row-major, V LDS-transposed.
__global__ __launch_bounds__(256) void gemm_qkv(
    const u16* __restrict__ Xp, const u16* __restrict__ Wpk,
    u16* __restrict__ Qb, u16* __restrict__ Kb, u16* __restrict__ Vtb,
    float qscale) {
  __shared__ __align__(16) u16 smem[16896];       // A dbuf 2x8K | V-transpose reuse
  const int t = threadIdx.x, lane = t & 63, wave = t >> 6;
  const int bn0 = blockIdx.x * 128, bm0 = blockIdx.y * 128;
  const int wr = wave >> 1, wc = wave & 1;
  const int colbase = bn0 + wc * 64;
  const int w = colbase >> 9;                     // 0=Wq 1=Wk 2=Wv
  const int cb16 = (colbase & 511) >> 4;          // base c16 within weight
  const u16* Bf = Wpk + (size_t)w * 262144;
  const u16* Ag = Xp + (size_t)bm0 * 512;
  f32x4 acc[4][4] = {};
  stage_rows<32>(Ag, 512, smem, wave, lane);
  __syncthreads();
  int cur = 0;
  for (int kt = 0; kt < 512; kt += 64) {
    if (kt < 448)
      stage_rows<32>(Ag + kt + 64, 512, smem + (cur ^ 1) * 8192, wave, lane);
    u16* Asc = smem + cur * 8192;
#pragma unroll
    for (int ks = 0; ks < 2; ++ks) {
      const int kc = (kt >> 5) + ks;
      bf16x8 af[4], bfr[4];
#pragma unroll
      for (int n = 0; n < 4; ++n)
        bfr[n] = *(const bf16x8*)(Bf + (size_t)((cb16 + n) * 16 + kc) * 512 + lane * 8);
#pragma unroll
      for (int m = 0; m < 4; ++m)
        af[m] = frag_read(Asc, wr * 64 + m * 16 + (lane & 15), ks * 4 + (lane >> 4));
#pragma unroll
      for (int m = 0; m < 4; ++m)
#pragma unroll
        for (int n = 0; n < 4; ++n)
          acc[m][n] = mfma16(af[m], bfr[n], acc[m][n]);
    }
    __syncthreads();   // drains next-tile loads (landed under compute) + read fence
    cur ^= 1;
  }
  const int cl = lane & 15, rg = (lane >> 4) * 4;
  if (bn0 >= 1024) {
    // ---- V region: transpose through LDS, then coalesced stores
#pragma unroll
    for (int m = 0; m < 4; ++m)
#pragma unroll
      for (int n = 0; n < 4; ++n) {
        const int dvL = wc * 64 + n * 16 + cl;
        const int rowL0 = wr * 64 + m * 16 + rg;
        u16x4 pk;
#pragma unroll
        for (int r = 0; r < 4; ++r) pk[r] = f2bf(acc[m][n][r]);
        *(u16x4*)(smem + dvL * 132 + rowL0) = pk;
      }
    __syncthreads();
    const int dvg0 = bn0 - 1024;
#pragma unroll
    for (int i = 0; i < 16; ++i) {
      const int idx = i * 256 + t;          // 4096 u16x4 total
      const int dv = idx >> 5, ch = (idx & 31) * 4;
      const u16x4 v = *(const u16x4*)(smem + dv * 132 + ch);
      *(u16x4*)(Vtb + (size_t)(dvg0 + dv) * 8192 + bm0 + ch) = v;
    }
  } else {
    u16* dst = (bn0 >= 512) ? Kb : Qb;
    const float al = (bn0 >= 512) ? 1.0f : qscale;
    const int cb = (bn0 & 511) + wc * 64;
#pragma unroll
    for (int m = 0; m < 4; ++m)
#pragma unroll
      for (int n = 0; n < 4; ++n) {
        const int col = cb + n * 16 + cl;
#pragma unroll
        for (int r = 0; r < 4; ++r) {
          const int row = bm0 + wr * 64 + m * 16 + rg + r;
          dst[(size_t)row * 512 + col] = f2bf(acc[m][n][r] * al);
        }
      }
  }
}

// ---------------------------------------------------------------------------
// FUSED out-proj + bias + residual + LayerNorm + NCHW transpose.
// grid 256 (Wo traffic 128MB, L2-resident), 512 threads = 8 waves (2/SIMD):
// wave owns 64 cols (4 B-frags/kc). 32 rows/block.
__global__ __launch_bounds__(512) void gemm_ln(
    const u16* __restrict__ A, const u16* __restrict__ Wpk,
    const u16* __restrict__ residb, const float* __restrict__ bias,
    const float* __restrict__ gamma, const float* __restrict__ beta,
    float* __restrict__ out) {
  __shared__ __align__(16) u16 smem[35200];          // As 32x64 | fsm reuse (70.4KB)
  __shared__ float redsum[8][32], redsq[8][32], srow[32][2];
  const int t = threadIdx.x, lane = t & 63, wave = t >> 6;
  const int m0 = blockIdx.x * 32;
  const int b = m0 >> 10, s0 = m0 & 1023;
  u16* As = smem;
  const u16* Bf = Wpk + (size_t)3 * 262144;        // Wo
  const u16* Ag = A + (size_t)m0 * 512;
  f32x4 acc[2][4] = {};
  for (int kt = 0; kt < 512; kt += 64) {
    __syncthreads();
    if (wave < 4) stage_rows<8>(Ag + kt, 512, As, wave, lane);  // 32 rows of A
    __syncthreads();
#pragma unroll
    for (int ks = 0; ks < 2; ++ks) {
      const int kc = (kt >> 5) + ks;
      bf16x8 af[2], bfr[4];
#pragma unroll
      for (int n = 0; n < 4; ++n)
        bfr[n] = *(const bf16x8*)(Bf + (size_t)((wave * 4 + n) * 16 + kc) * 512 + lane * 8);
#pragma unroll
      for (int m = 0; m < 2; ++m)
        af[m] = frag_read(As, m * 16 + (lane & 15), ks * 4 + (lane >> 4));
#pragma unroll
      for (int m = 0; m < 2; ++m)
#pragma unroll
        for (int n = 0; n < 4; ++n)
          acc[m][n] = mfma16(af[m], bfr[n], acc[m][n]);
    }
  }
  // ---- epilogue: bias + resid, partial LN stats, stage to LDS (transposed)
  __syncthreads();                 // done reading staging LDS; reuse as float
  float* fsm = (float*)smem;       // per wave: [64 cols][33 rows]
  float* fw = fsm + wave * (64 * 33);
  const int cl = lane & 15, rg = (lane >> 4) * 4;
  float psum[8], psq[8];
#pragma unroll
  for (int i = 0; i < 8; ++i) { psum[i] = 0.f; psq[i] = 0.f; }
#pragma unroll
  for (int m = 0; m < 2; ++m)
#pragma unroll
    for (int n = 0; n < 4; ++n) {
      const int col_l = n * 16 + cl;
      const int col = wave * 64 + col_l;
      const float bi = bias[col];
#pragma unroll
      for (int r = 0; r < 4; ++r) {
        const int row_l = m * 16 + rg + r;
        const float v = acc[m][n][r] + bi
                      + bf2f(residb[(size_t)(m0 + row_l) * 512 + col]);
        fw[col_l * 33 + row_l] = v;
        psum[m * 4 + r] += v;
        psq[m * 4 + r] += v * v;
      }
    }
#pragma unroll
  for (int i = 0; i < 8; ++i) {
#pragma unroll
    for (int off = 8; off >= 1; off >>= 1) {
      psum[i] += __shfl_xor(psum[i], off);
      psq[i]  += __shfl_xor(psq[i], off);
    }
  }
  if (cl == 0) {
#pragma unroll
    for (int m = 0; m < 2; ++m)
#pragma unroll
      for (int r = 0; r < 4; ++r) {
        const int row_l = m * 16 + rg + r;
        redsum[wave][row_l] = psum[m * 4 + r];
        redsq[wave][row_l]  = psq[m * 4 + r];
      }
  }
  __syncthreads();
  if (t < 32) {
    float s = 0.f, q = 0.f;
#pragma unroll
    for (int w = 0; w < 8; ++w) { s += redsum[w][t]; q += redsq[w][t]; }
    const float mean = s * (1.f / 512.f);
    const float var = q * (1.f / 512.f) - mean * mean;
    srow[t][0] = mean;
    srow[t][1] = rsqrtf(var + 1e-5f);
  }
  __syncthreads();
  // ---- normalize + transposed write (contiguous 128B per channel)
  const int row = t & 31, cgrp = t >> 5;           // cgrp 0..15
  const float mean = srow[row][0], rstd = srow[row][1];
  float* outb = out + (size_t)b * 512 * 1024 + s0 + row;
#pragma unroll 4
  for (int cc = 0; cc < 32; ++cc) {
    const int col = cc * 16 + cgrp;
    const float v = (fsm[(col >> 6) * (64 * 33) + (col & 63) * 33 + row] - mean) * rstd;
    outb[(size_t)col * 1024] = v * gamma[col] + beta[col];
  }
}

// ---------------------------------------------------------------------------
// Flash attention (best-known r8/r15 form): split-K across wave pairs + merge.
// Grid 1024; wg -> b = wg&7 (XCD-resident K/V), h = (wg>>3)&7, qt = wg>>6.
// Block = 4 waves: qsub = wave&1 (32 q-rows), half = wave>>1 (kv tiles
// half*8 .. half*8+7). Single-buffered K/V per half (32KB LDS).
// Swapped-operand 32x32x16 MFMA, in-register softmax (v_exp_f32, Q prescaled
// by log2e/sqrt(dk)), cvt_pk + permlane32_swap, defer-max, setprio.
__global__ __launch_bounds__(256, 4) void attn(
    const u16* __restrict__ Qb, const u16* __restrict__ Kb,
    const u16* __restrict__ Vt, u16* __restrict__ Ob) {
  __shared__ __align__(16) u16 Ks[2][64 * 64];
  __shared__ __align__(16) u16 Vs[2][64 * 64];
  const int t = threadIdx.x, lane = t & 63, wave = t >> 6;
  const int wg = blockIdx.x;
  const int b = wg & 7, h = (wg >> 3) & 7, qt = wg >> 6;
  const int qsub = wave & 1, half = wave >> 1;
  const int ql = lane & 31, hl = lane >> 5;
  const int q0 = qt * 64 + qsub * 32;
  bf16x8 bq[4];
  {
    const u16* qrow = Qb + ((size_t)b * 1024 + q0 + ql) * 512 + h * 64 + hl * 8;
#pragma unroll
    for (int c = 0; c < 4; ++c) bq[c] = *(const bf16x8*)(qrow + c * 16);
  }
  f32x16 ot[2] = {};
  float m_run = -1e30f, l_run = 0.f;
  u16* stg_dst = qsub ? Vs[half] : Ks[half];
  for (int i = 0; i < 8; ++i) {
    const int kb = half * 512 + i * 64;
    {
      const int r_in = lane >> 3, slot = lane & 7;
      const u16* src; size_t gs;
      if (qsub) { src = Vt + (size_t)(h * 64) * 8192 + (size_t)b * 1024 + kb; gs = 8192; }
      else      { src = Kb + ((size_t)b * 1024 + kb) * 512 + h * 64;          gs = 512; }
#pragma unroll
      for (int j = 0; j < 8; ++j) {
        const int row = j * 8 + r_in;
        const int ss = slot ^ (row & 7);
        gl2lds16(src + (size_t)row * gs + ss * 8, stg_dst + j * 512);
      }
    }
    __syncthreads();
    f32x16 st[2] = {};
    __builtin_amdgcn_s_setprio(1);
#pragma unroll
    for (int c = 0; c < 4; ++c) {
      bf16x8 a0 = frag_read(Ks[half], ql, c * 2 + hl);
      bf16x8 a1 = frag_read(Ks[half], 32 + ql, c * 2 + hl);
      st[0] = mfma32(a0, bq[c], st[0]);
      st[1] = mfma32(a1, bq[c], st[1]);
    }
    __builtin_amdgcn_s_setprio(0);
    float m0[8];
#pragma unroll
    for (int i2 = 0; i2 < 8; ++i2)
      m0[i2] = fmaxf(fmaxf(st[0][i2], st[0][i2 + 8]), fmaxf(st[1][i2], st[1][i2 + 8]));
#pragma unroll
    for (int i2 = 0; i2 < 4; ++i2) m0[i2] = fmaxf(m0[i2], m0[i2 + 4]);
    float mx = fmaxf(fmaxf(m0[0], m0[1]), fmaxf(m0[2], m0[3]));
    mx = fmaxf(mx, __shfl_xor(mx, 32));
    if (!__all(mx <= m_run + 8.f)) {
      const float mn = fmaxf(m_run, mx);
      const float sc = fexp2(m_run - mn);
      m_run = mn;
      l_run *= sc;
      ot[0] *= sc;
      ot[1] *= sc;
    }
#pragma unroll
    for (int i2 = 0; i2 < 16; ++i2) {
      st[0][i2] = fexp2(st[0][i2] - m_run);
      st[1][i2] = fexp2(st[1][i2] - m_run);
    }
    float s0[8];
#pragma unroll
    for (int i2 = 0; i2 < 8; ++i2)
      s0[i2] = (st[0][i2] + st[0][i2 + 8]) + (st[1][i2] + st[1][i2 + 8]);
#pragma unroll
    for (int i2 = 0; i2 < 4; ++i2) s0[i2] = s0[i2] + s0[i2 + 4];
    float rs = (s0[0] + s0[1]) + (s0[2] + s0[3]);
    rs += __shfl_xor(rs, 32);
    l_run += rs;
    __builtin_amdgcn_s_setprio(1);
#pragma unroll
    for (int c = 0; c < 4; ++c) {
      const int kf = c >> 1, i0 = (c & 1) * 4;
      u32 w0 = cvt_pk_bf16(st[kf][2 * i0 + 0], st[kf][2 * i0 + 1]);
      u32 w1 = cvt_pk_bf16(st[kf][2 * i0 + 2], st[kf][2 * i0 + 3]);
      u32 w2 = cvt_pk_bf16(st[kf][2 * i0 + 4], st[kf][2 * i0 + 5]);
      u32 w3 = cvt_pk_bf16(st[kf][2 * i0 + 6], st[kf][2 * i0 + 7]);
      perm32swap(w0, w2);
      perm32swap(w1, w3);
      u32x4 wv; wv.x = w0; wv.y = w1; wv.z = w2; wv.w = w3;
      bf16x8 bp = *(bf16x8*)&wv;
      bf16x8 v0 = frag_read(Vs[half], ql, c * 2 + hl);
      bf16x8 v1 = frag_read(Vs[half], 32 + ql, c * 2 + hl);
      ot[0] = mfma32(v0, bp, ot[0]);
      ot[1] = mfma32(v1, bp, ot[1]);
    }
    __builtin_amdgcn_s_setprio(0);
    __syncthreads();
  }
  float* Om = (float*)&Ks[0][0] + qsub * 2048;
  float* Ml = (float*)&Vs[0][0];
  if (wave >= 2) {
#pragma unroll
    for (int df = 0; df < 2; ++df)
#pragma unroll
      for (int r = 0; r < 16; ++r) {
        const int dr = (r & 3) + 8 * (r >> 2) + 4 * hl;
        Om[(df * 32 + dr) * 32 + ql] = ot[df][r];
      }
    if (hl == 0) {
      Ml[qsub * 64 + ql] = m_run;
      Ml[qsub * 64 + 32 + ql] = l_run;
    }
    __syncthreads();
  } else {
    __syncthreads();
    const float m2 = Ml[qsub * 64 + ql];
    const float l2 = Ml[qsub * 64 + 32 + ql];
    const float m = fmaxf(m_run, m2);
    const float a = fexp2(m_run - m);
    const float bsc = fexp2(m2 - m);
    const float inv = 1.f / (l_run * a + l2 * bsc);
    u16* orow = Ob + ((size_t)b * 1024 + q0 + ql) * 512 + h * 64;
#pragma unroll
    for (int df = 0; df < 2; ++df)
#pragma unroll
      for (int r = 0; r < 16; ++r) {
        const int dr = (r & 3) + 8 * (r >> 2) + 4 * hl;
        const float v = ot[df][r] * a + Om[(df * 32 + dr) * 32 + ql] * bsc;
        orow[df * 32 + dr] = f2bf(v * inv);
      }
  }
}

// ---------------------------------------------------------------------------
extern "C" void kernel_launch(void* const* d_in, const int* in_sizes, int n_in,
                              void* d_out, int out_size, void* d_ws, size_t ws_size,
                              hipStream_t stream) {
  const float* x     = (const float*)d_in[0];
  const float* Wq    = (const float*)d_in[1];
  const float* Wk    = (const float*)d_in[2];
  const float* Wv    = (const float*)d_in[3];
  const float* Wo    = (const float*)d_in[4];
  const float* bo    = (const float*)d_in[5];
  const float* gamma = (const float*)d_in[6];
  const float* beta  = (const float*)d_in[7];
  char* ws = (char*)d_ws;
  const size_t MB = 1048576;
  u16*   Xp    = (u16*)(ws);             //  8 MB bf16 (8192,512): x + PE (also residual)
  u16*   Wpk   = (u16*)(ws + 8 * MB);    //  2 MB packed weight fragments [q][k][v][o]
  u16*   Qb    = (u16*)(ws + 10 * MB);   //  8 MB (prescaled)
  u16*   Kb    = (u16*)(ws + 18 * MB);   //  8 MB
  u16*   Vtb   = (u16*)(ws + 26 * MB);   //  8 MB bf16 V^T (512, 8192)
  u16*   Ob    = (u16*)(ws + 34 * MB);   //  8 MB attention out

  // merged: x+PE prep (z<8) and weight fragment packing (z==8)
  prep_x<<<dim3(32, 16, 9), 256, 0, stream>>>(x, Xp, Wq, Wk, Wv, Wo, Wpk);
  // fused QKV: Q scaled by (1/sqrt(dk))*log2(e); V written transposed
  gemm_qkv<<<dim3(12, 64), 256, 0, stream>>>(Xp, Wpk, Qb, Kb, Vtb,
                                             0.125f * 1.44269504088896f);
  attn<<<1024, 256, 0, stream>>>(Qb, Kb, Vtb, Ob);
  // fused out-proj + bias + residual + LayerNorm + NCHW transpose
  gemm_ln<<<256, 512, 0, stream>>>(Ob, Wpk, Xp, bo, gamma, beta,
                                   (float*)d_out);
}